// Round 7
// baseline (519.516 us; speedup 1.0000x reference)
//
#include <hip/hip_runtime.h>

#define NROWS 500000
#define DD 128
#define NSTACK 12
#define BNEPS 1e-3f
#define NCOL 50
#define TRS 51            // trow stride in floats (204B: odd stride -> <=2-way LDS banking)

// packed tail-weight blob layout (floats)
#define WY   0            // [0,1056): y-part weights, layer i at 8*i*(i-1), 16*i floats
#define WFo  1056         // [1056,1152): wf[0..95]
#define WSC  1152         // [1152,1200): SC = gamma*rsqrt(var+eps)
#define WSH  1200         // [1200,1248): SH = beta - mean*SC
#define WBF  1248         // [1248,1250): bf
#define WTOT 1250

typedef float  v2f    __attribute__((ext_vector_type(2)));
typedef float  v4f    __attribute__((ext_vector_type(4)));
typedef float  f32x4  __attribute__((ext_vector_type(4)));
typedef __bf16 bf16x8 __attribute__((ext_vector_type(8)));

__device__ __forceinline__ unsigned short f2bf_rn(float f) {
    unsigned u = __float_as_uint(f);
    return (unsigned short)((u + 0x7FFFu + ((u >> 16) & 1u)) >> 16);
}

// -------- workspace layout (bytes) --------
//  [0,     16384)  ushort frag[4][4][64][8]   B fragments, bf16, MFMA fragment order
//  [16800, 21800)  float  WT[1250]            packed tail weights (see above)

// One-shot prep: build B fragments + packed tail-weight blob.
__global__ void prep_kernel(
    const float* __restrict__ w0,  const float* __restrict__ w1,
    const float* __restrict__ w2,  const float* __restrict__ w3,
    const float* __restrict__ w4,  const float* __restrict__ w5,
    const float* __restrict__ w6,  const float* __restrict__ w7,
    const float* __restrict__ w8,  const float* __restrict__ w9,
    const float* __restrict__ w10, const float* __restrict__ w11,
    const float* __restrict__ gamma_, const float* __restrict__ beta_,
    const float* __restrict__ mean_,  const float* __restrict__ var_,
    const float* __restrict__ wf,     const float* __restrict__ bfv,
    unsigned short* __restrict__ frag, float* __restrict__ wt)
{
    const float* ws[NSTACK] = {w0,w1,w2,w3,w4,w5,w6,w7,w8,w9,w10,w11};
    const int f = blockIdx.x * 256 + threadIdx.x;

    if (f < 8192) {
        // B fragments: f -> (kt,nt,lane,j); k = kt*32 + (lane>>4)*8 + j,
        // n = nt*16 + (lane&15). n<48: ws[n>>2][16*(n>>2)+4k+(n&3)];
        // n in {48,49}: wf[96+2k+(n-48)]; n>=50: 0 pad.
        const int j    = f & 7;
        const int lane = (f >> 3) & 63;
        const int nt   = (f >> 9) & 3;
        const int kt   = f >> 11;
        const int k    = kt * 32 + (lane >> 4) * 8 + j;
        const int n    = nt * 16 + (lane & 15);
        float val = 0.f;
        if (n < 48) {
            const int i = n >> 2, u = n & 3;
            val = ws[i][16 * i + 4 * k + u];
        } else if (n < NCOL) {
            val = wf[96 + 2 * k + (n - 48)];
        }
        frag[f] = f2bf_rn(val);
        return;
    }

    const int g = f - 8192;
    if (g >= WTOT) return;

    float val;
    if (g < WFo) {
        // y-part weights: find layer L with 8L(L-1) <= g < 8(L+1)L
        int L = 1;
#pragma unroll 1
        for (int t = 2; t <= 11; ++t)
            if (g >= 8 * t * (t - 1)) L = t;
        val = ws[L][g - 8 * L * (L - 1)];
    } else if (g < WSC) {
        val = wf[g - WFo];
    } else if (g < WSH) {
        const int u = g - WSC;
        val = gamma_[u] * __frsqrt_rn(var_[u] + BNEPS);
    } else if (g < WBF) {
        const int u = g - WSH;
        const float s = gamma_[u] * __frsqrt_rn(var_[u] + BNEPS);
        val = beta_[u] - mean_[u] * s;
    } else {
        val = bfv[g - WBF];
    }
    wt[g] = val;
}

// Main kernel: 4 waves x 64 rows = 256 rows/block, one tile per block.
// DESIGN GOAL: tiny instruction footprint (~2KB) — all loops rolled except
// where acc indexing must be static. The previous fully-unrolled tail
// (s_load weights need compile-time offsets) was ~25KB of straight-line
// code: I$-streaming stalls explain the 98%-idle counter signature.
// Tail weights come from LDS (broadcast reads, runtime-indexed); y values
// are written back into trow over the consumed T columns (in-place concat).
__global__ __launch_bounds__(256, 2) void predict_kernel(
    const float* __restrict__ x,
    const unsigned short* __restrict__ frag,
    const float* __restrict__ WT,
    float* __restrict__ out)
{
    __shared__ __align__(16) float trow[256 * TRS];   // 52224 B
    __shared__ __align__(16) float wlds[WTOT];        // 5000 B -> total 57224, 2 blk/CU

    const int tid  = threadIdx.x;
    const int lane = tid & 63;
    const int wv   = tid >> 6;
    const int rowbase = blockIdx.x * 256 + wv * 64;
    const int m = lane & 15;
    const int q = lane >> 4;

    // ---- stage packed tail weights (5KB, contiguous, L2-hot) ----
#pragma unroll 1
    for (int e = tid; e < WTOT; e += 256)
        wlds[e] = WT[e];

    // ---- Phase 1: MFMA GEMM (kt loop rolled; mt/nt static for acc) ----
    const float* arow[4];
#pragma unroll
    for (int mt = 0; mt < 4; ++mt) {
        int r = rowbase + mt * 16 + m;
        if (r > NROWS - 1) r = NROWS - 1;             // tail clamp (stores predicated)
        arow[mt] = x + (size_t)r * DD + q * 8;
    }

    f32x4 acc[4][4];
#pragma unroll
    for (int mt = 0; mt < 4; ++mt)
#pragma unroll
        for (int nt = 0; nt < 4; ++nt) acc[mt][nt] = (f32x4){0.f, 0.f, 0.f, 0.f};

#pragma unroll 1
    for (int kt = 0; kt < 4; ++kt) {
        bf16x8 bfrag[4];
#pragma unroll
        for (int nt = 0; nt < 4; ++nt)
            bfrag[nt] = *(const bf16x8*)(frag + (((kt * 4 + nt) * 64 + lane) << 3));
#pragma unroll
        for (int mt = 0; mt < 4; ++mt) {
            const v4f a0 = *(const v4f*)(arow[mt] + kt * 32);
            const v4f a1 = *(const v4f*)(arow[mt] + kt * 32 + 4);
            bf16x8 av;
#pragma unroll
            for (int e = 0; e < 4; ++e) {
                av[e]     = (__bf16)a0[e];            // v_cvt_pk_bf16_f32
                av[4 + e] = (__bf16)a1[e];
            }
#pragma unroll
            for (int nt = 0; nt < 4; ++nt)
                acc[mt][nt] = __builtin_amdgcn_mfma_f32_16x16x32_bf16(
                    av, bfrag[nt], acc[mt][nt], 0, 0, 0);
        }
    }

    // ---- Phase 1.5: C-frag -> row-major LDS (wave-private region) ----
    // C/D layout: col = lane&15, row = (lane>>4)*4 + reg   [m89/m91]
    float* tr = &trow[wv * 64 * TRS];
#pragma unroll
    for (int mt = 0; mt < 4; ++mt)
#pragma unroll
        for (int nt = 0; nt < 4; ++nt) {
            const int c = nt * 16 + m;
            if (c < NCOL) {
#pragma unroll
                for (int r = 0; r < 4; ++r)
                    tr[(mt * 16 + q * 4 + r) * TRS + c] = acc[mt][nt][r];
            }
        }

    __syncthreads();   // wlds visible to all waves (also orders trow, harmless)

    // ---- Phase 2: per-lane recurrence, rolled; y overwrites T cols in trow ----
    float* myT = &trow[(wv * 64 + lane) * TRS];

#pragma unroll 1
    for (int i = 0; i < NSTACK; ++i) {
        v2f a01 = *(const v2f*)(myT + 4 * i);         // T cols 4i..4i+3 (bias part)
        v2f a23 = *(const v2f*)(myT + 4 * i + 2);
        const float* wyi = &wlds[WY + 8 * i * (i - 1)];
#pragma unroll 1
        for (int jj = 0; jj < i; ++jj) {
            // h ordering: mr=4*jj+t uses y_{i-1-jj}[t] and W row 4*jj+t
            const v2f yv01 = *(const v2f*)(myT + 4 * (i - 1 - jj));
            const v2f yv23 = *(const v2f*)(myT + 4 * (i - 1 - jj) + 2);
            const float* wr = wyi + 16 * jj;          // 4 rows x 4 cols
            a01 += (v2f){yv01.x, yv01.x} * (*(const v2f*)(wr + 0));
            a23 += (v2f){yv01.x, yv01.x} * (*(const v2f*)(wr + 2));
            a01 += (v2f){yv01.y, yv01.y} * (*(const v2f*)(wr + 4));
            a23 += (v2f){yv01.y, yv01.y} * (*(const v2f*)(wr + 6));
            a01 += (v2f){yv23.x, yv23.x} * (*(const v2f*)(wr + 8));
            a23 += (v2f){yv23.x, yv23.x} * (*(const v2f*)(wr + 10));
            a01 += (v2f){yv23.y, yv23.y} * (*(const v2f*)(wr + 12));
            a23 += (v2f){yv23.y, yv23.y} * (*(const v2f*)(wr + 14));
        }
        const v2f sc01 = *(const v2f*)(&wlds[WSC + 4 * i]);
        const v2f sc23 = *(const v2f*)(&wlds[WSC + 4 * i + 2]);
        const v2f sh01 = *(const v2f*)(&wlds[WSH + 4 * i]);
        const v2f sh23 = *(const v2f*)(&wlds[WSH + 4 * i + 2]);
        v2f r01 = a01 * sc01 + sh01;
        v2f r23 = a23 * sc23 + sh23;
        r01.x = fmaxf(r01.x, 0.f); r01.y = fmaxf(r01.y, 0.f);
        r23.x = fmaxf(r23.x, 0.f); r23.y = fmaxf(r23.y, 0.f);
        *(v2f*)(myT + 4 * i)     = r01;               // y_i replaces T cols 4i..4i+3
        *(v2f*)(myT + 4 * i + 2) = r23;
    }

    // ---- Phase 3: final logits (rolled) + softmax ----
    v2f l01 = *(const v2f*)(myT + 48) + *(const v2f*)(&wlds[WBF]);
#pragma unroll 1
    for (int jj = 0; jj < NSTACK; ++jj) {
        // mr=4*jj+t uses y_{11-jj}[t] and wf rows 2*(4jj+t)
        const v2f yv01 = *(const v2f*)(myT + 4 * (11 - jj));
        const v2f yv23 = *(const v2f*)(myT + 4 * (11 - jj) + 2);
        const float* wr = &wlds[WFo + 8 * jj];
        l01 += (v2f){yv01.x, yv01.x} * (*(const v2f*)(wr + 0));
        l01 += (v2f){yv01.y, yv01.y} * (*(const v2f*)(wr + 2));
        l01 += (v2f){yv23.x, yv23.x} * (*(const v2f*)(wr + 4));
        l01 += (v2f){yv23.y, yv23.y} * (*(const v2f*)(wr + 6));
    }

    const float mx = fmaxf(l01.x, l01.y);
    const float e0 = __expf(l01.x - mx);
    const float e1 = __expf(l01.y - mx);
    const float inv = 1.0f / (e0 + e1);

    const int row = rowbase + lane;
    if (row < NROWS)
        *(v2f*)(out + (size_t)row * 2) = (v2f){e0 * inv, e1 * inv};
}

extern "C" void kernel_launch(void* const* d_in, const int* in_sizes, int n_in,
                              void* d_out, int out_size, void* d_ws, size_t ws_size,
                              hipStream_t stream) {
    const float* x   = (const float*)d_in[0];
    const float* w0  = (const float*)d_in[1];
    const float* w1  = (const float*)d_in[2];
    const float* w2  = (const float*)d_in[3];
    const float* w3  = (const float*)d_in[4];
    const float* w4  = (const float*)d_in[5];
    const float* w5  = (const float*)d_in[6];
    const float* w6  = (const float*)d_in[7];
    const float* w7  = (const float*)d_in[8];
    const float* w8  = (const float*)d_in[9];
    const float* w9  = (const float*)d_in[10];
    const float* w10 = (const float*)d_in[11];
    const float* w11 = (const float*)d_in[12];
    const float* gm  = (const float*)d_in[13];
    const float* bt  = (const float*)d_in[14];
    const float* mn  = (const float*)d_in[15];
    const float* vr  = (const float*)d_in[16];
    const float* wf  = (const float*)d_in[17];
    const float* bf  = (const float*)d_in[18];
    float* out = (float*)d_out;

    unsigned short* frag = (unsigned short*)d_ws;
    float* WT = (float*)((char*)d_ws + 16800);

    // prep: 32 blocks for 8192 frag entries + 5 blocks for the 1250-float blob
    hipLaunchKernelGGL(prep_kernel, dim3(37), dim3(256), 0, stream,
                       w0, w1, w2, w3, w4, w5, w6, w7, w8, w9, w10, w11,
                       gm, bt, mn, vr, wf, bf, frag, WT);

    dim3 block(256);
    dim3 grid((NROWS + 255) / 256);   // 256 rows per block
    hipLaunchKernelGGL(predict_kernel, grid, block, 0, stream,
                       x, frag, WT, out);
}

// Round 8
// 438.311 us; speedup vs baseline: 1.1853x; 1.1853x over previous
//
#include <hip/hip_runtime.h>

#define NROWS 500000
#define DD 128
#define NSTACK 12
#define BNEPS 1e-3f
#define NCOL 50
#define TRS 51            // trow stride in floats (204B: odd stride -> <=2-way LDS banking)
#define GRID ((NROWS + 255) / 256)   // 1954 blocks, 256 rows each
#define TWS_OFF (1u << 24)           // Tfrag staging at +16MB in d_ws (needs 128MB; ws is ~1GB)

typedef float  v2f    __attribute__((ext_vector_type(2)));
typedef float  v4f    __attribute__((ext_vector_type(4)));
typedef float  f32x4  __attribute__((ext_vector_type(4)));
typedef __bf16 bf16x8 __attribute__((ext_vector_type(8)));

__device__ __forceinline__ unsigned short f2bf_rn(float f) {
    unsigned u = __float_as_uint(f);
    return (unsigned short)((u + 0x7FFFu + ((u >> 16) & 1u)) >> 16);
}

// -------- workspace layout (bytes) --------
//  [0,     16384)  ushort frag[4][4][64][8]   B fragments, bf16, MFMA fragment order
//  [16384, 16576)  float  SC[48]              gamma * rsqrt(var+eps)
//  [16576, 16768)  float  SH[48]              beta  - mean * SC
//  [16768, 16776)  float  BF2[2]              final bias
//  [16MB, 16MB+128MB) float Tws               C-fragments, [wavetile][mt*4+nt][lane][4]

__global__ void prep_kernel(
    const float* __restrict__ w0,  const float* __restrict__ w1,
    const float* __restrict__ w2,  const float* __restrict__ w3,
    const float* __restrict__ w4,  const float* __restrict__ w5,
    const float* __restrict__ w6,  const float* __restrict__ w7,
    const float* __restrict__ w8,  const float* __restrict__ w9,
    const float* __restrict__ w10, const float* __restrict__ w11,
    const float* __restrict__ gamma_, const float* __restrict__ beta_,
    const float* __restrict__ mean_,  const float* __restrict__ var_,
    const float* __restrict__ wf,     const float* __restrict__ bfv,
    unsigned short* __restrict__ frag, float* __restrict__ sc,
    float* __restrict__ sh, float* __restrict__ bf2)
{
    const float* ws[NSTACK] = {w0,w1,w2,w3,w4,w5,w6,w7,w8,w9,w10,w11};
    const int f    = blockIdx.x * 256 + threadIdx.x;   // 0..8191
    const int j    = f & 7;
    const int lane = (f >> 3) & 63;
    const int nt   = (f >> 9) & 3;
    const int kt   = f >> 11;
    const int k    = kt * 32 + (lane >> 4) * 8 + j;
    const int n    = nt * 16 + (lane & 15);

    float val = 0.f;
    if (n < 48) {
        const int i = n >> 2, u = n & 3;
        val = ws[i][16 * i + 4 * k + u];
    } else if (n < NCOL) {
        val = wf[96 + 2 * k + (n - 48)];
    }
    frag[f] = f2bf_rn(val);

    if (blockIdx.x == 0) {
        if (threadIdx.x < 48) {
            const float s = gamma_[threadIdx.x] * __frsqrt_rn(var_[threadIdx.x] + BNEPS);
            sc[threadIdx.x] = s;
            sh[threadIdx.x] = beta_[threadIdx.x] - mean_[threadIdx.x] * s;
        }
        if (threadIdx.x < 2) bf2[threadIdx.x] = bfv[threadIdx.x];
    }
}

// ================= Kernel A: GEMM-only streamer =================
// No LDS, no tail: streams x at ~full VMEM duty, stores C-fragments to
// global Tws in fragment-native layout (16 x dwordx4, 1KB coalesced each).
__global__ __launch_bounds__(256, 4) void gemm_kernel(
    const float* __restrict__ x,
    const unsigned short* __restrict__ frag,
    float* __restrict__ Tws)
{
    const int tid  = threadIdx.x;
    const int lane = tid & 63;
    const int wv   = tid >> 6;
    const int rowbase = blockIdx.x * 256 + wv * 64;
    const int m = lane & 15;
    const int q = lane >> 4;

    const float* arow[4];
#pragma unroll
    for (int mt = 0; mt < 4; ++mt) {
        int r = rowbase + mt * 16 + m;
        if (r > NROWS - 1) r = NROWS - 1;             // tail clamp
        arow[mt] = x + (size_t)r * DD + q * 8;
    }

    f32x4 acc[4][4];
#pragma unroll
    for (int mt = 0; mt < 4; ++mt)
#pragma unroll
        for (int nt = 0; nt < 4; ++nt) acc[mt][nt] = (f32x4){0.f, 0.f, 0.f, 0.f};

#pragma unroll
    for (int kt = 0; kt < 4; ++kt) {
        bf16x8 bfrag[4];
#pragma unroll
        for (int nt = 0; nt < 4; ++nt)
            bfrag[nt] = *(const bf16x8*)(frag + (((kt * 4 + nt) * 64 + lane) << 3));
#pragma unroll
        for (int mt = 0; mt < 4; ++mt) {
            const v4f a0 = *(const v4f*)(arow[mt] + kt * 32);
            const v4f a1 = *(const v4f*)(arow[mt] + kt * 32 + 4);
            bf16x8 av;
#pragma unroll
            for (int e = 0; e < 4; ++e) {
                av[e]     = (__bf16)a0[e];            // v_cvt_pk_bf16_f32
                av[4 + e] = (__bf16)a1[e];
            }
#pragma unroll
            for (int nt = 0; nt < 4; ++nt)
                acc[mt][nt] = __builtin_amdgcn_mfma_f32_16x16x32_bf16(
                    av, bfrag[nt], acc[mt][nt], 0, 0, 0);
        }
    }

    // fragment-native store: [wavetile][mt*4+nt][lane][0..3], 1KB/instr coalesced
    float* tb = Tws + ((size_t)(blockIdx.x * 4 + wv) << 12) + (lane << 2);
#pragma unroll
    for (int mt = 0; mt < 4; ++mt)
#pragma unroll
        for (int nt = 0; nt < 4; ++nt)
            *(v4f*)(tb + ((mt * 4 + nt) << 8)) = acc[mt][nt];
}

// ================= Kernel B: tail-only =================
// Loads C-fragments (coalesced), LDS-transposes, runs the recurrence
// (R5 structure verbatim: unrolled, s_load weights, dual accumulator chains).
__global__ __launch_bounds__(256, 3) void tail_kernel(
    const float* __restrict__ Tws,
    const float* __restrict__ w0,  const float* __restrict__ w1,
    const float* __restrict__ w2,  const float* __restrict__ w3,
    const float* __restrict__ w4,  const float* __restrict__ w5,
    const float* __restrict__ w6,  const float* __restrict__ w7,
    const float* __restrict__ w8,  const float* __restrict__ w9,
    const float* __restrict__ w10, const float* __restrict__ w11,
    const float* __restrict__ wf,
    const float* __restrict__ SCg, const float* __restrict__ SHg,
    const float* __restrict__ BFg,
    float* __restrict__ out)
{
    __shared__ __align__(16) float trow[256 * TRS];   // 52224 B -> 3 blocks/CU

    const int tid  = threadIdx.x;
    const int lane = tid & 63;
    const int wv   = tid >> 6;
    const int rowbase = blockIdx.x * 256 + wv * 64;
    const int m = lane & 15;
    const int q = lane >> 4;

    // ---- load fragments back (16 x dwordx4, coalesced) ----
    const float* tb = Tws + ((size_t)(blockIdx.x * 4 + wv) << 12) + (lane << 2);
    f32x4 acc[4][4];
#pragma unroll
    for (int mt = 0; mt < 4; ++mt)
#pragma unroll
        for (int nt = 0; nt < 4; ++nt)
            acc[mt][nt] = *(const v4f*)(tb + ((mt * 4 + nt) << 8));

    // ---- C-frag -> row-major LDS (wave-private region) ----
    // C/D layout: col = lane&15, row = (lane>>4)*4 + reg   [m89/m91]
    float* tr = &trow[wv * 64 * TRS];
#pragma unroll
    for (int mt = 0; mt < 4; ++mt)
#pragma unroll
        for (int nt = 0; nt < 4; ++nt) {
            const int c = nt * 16 + m;
            if (c < NCOL) {
#pragma unroll
                for (int r = 0; r < 4; ++r)
                    tr[(mt * 16 + q * 4 + r) * TRS + c] = acc[mt][nt][r];
            }
        }

    // ---- recurrence (per-lane), packed fp32, dual chains ----
    const float* myT = &trow[(wv * 64 + lane) * TRS];
    const float* ws[NSTACK] = {w0,w1,w2,w3,w4,w5,w6,w7,w8,w9,w10,w11};

    v2f y2[NSTACK * 2];                               // even-aligned pairs
#pragma unroll
    for (int i = 0; i < NSTACK; ++i) {
        v2f ac01[2], ac23[2];
        ac01[0] = *(const v2f*)(myT + 4 * i);         // ds_read_b64
        ac23[0] = *(const v2f*)(myT + 4 * i + 2);
        ac01[1] = (v2f){0.f, 0.f};
        ac23[1] = (v2f){0.f, 0.f};
        const float* wsi = ws[i];
#pragma unroll
        for (int mr = 0; mr < 4 * i; ++mr) {          // uniform idx -> s_load (K$)
            const int yi = (i - 1 - (mr >> 2)) * 4 + (mr & 3);
            const float hvs = y2[yi >> 1][yi & 1];
            const v2f hv2 = {hvs, hvs};               // op_sel splat
            ac01[mr & 1] += hv2 * (*(const v2f*)(wsi + 4 * mr));
            ac23[mr & 1] += hv2 * (*(const v2f*)(wsi + 4 * mr + 2));
        }
        const v2f a01 = ac01[0] + ac01[1];
        const v2f a23 = ac23[0] + ac23[1];
        const v2f sc01 = *(const v2f*)(SCg + 4 * i);
        const v2f sc23 = *(const v2f*)(SCg + 4 * i + 2);
        const v2f sh01 = *(const v2f*)(SHg + 4 * i);
        const v2f sh23 = *(const v2f*)(SHg + 4 * i + 2);
        v2f r01 = a01 * sc01 + sh01;
        v2f r23 = a23 * sc23 + sh23;
        r01.x = fmaxf(r01.x, 0.f); r01.y = fmaxf(r01.y, 0.f);
        r23.x = fmaxf(r23.x, 0.f); r23.y = fmaxf(r23.y, 0.f);
        y2[2 * i]     = r01;
        y2[2 * i + 1] = r23;
    }

    // ---- final logits + softmax ----
    v2f lc[2];
    lc[0] = *(const v2f*)(myT + 48) + *(const v2f*)BFg;
    lc[1] = (v2f){0.f, 0.f};
#pragma unroll
    for (int mr = 0; mr < 48; ++mr) {                 // uniform idx -> s_load (K$)
        const int yi = (11 - (mr >> 2)) * 4 + (mr & 3);
        const float hvs = y2[yi >> 1][yi & 1];
        const v2f hv2 = {hvs, hvs};
        lc[mr & 1] += hv2 * (*(const v2f*)(wf + 2 * mr));
    }
    const v2f l01 = lc[0] + lc[1];

    const float mx = fmaxf(l01.x, l01.y);
    const float e0 = __expf(l01.x - mx);
    const float e1 = __expf(l01.y - mx);
    const float inv = 1.0f / (e0 + e1);

    const int row = rowbase + lane;
    if (row < NROWS)
        *(v2f*)(out + (size_t)row * 2) = (v2f){e0 * inv, e1 * inv};
}

extern "C" void kernel_launch(void* const* d_in, const int* in_sizes, int n_in,
                              void* d_out, int out_size, void* d_ws, size_t ws_size,
                              hipStream_t stream) {
    const float* x   = (const float*)d_in[0];
    const float* w0  = (const float*)d_in[1];
    const float* w1  = (const float*)d_in[2];
    const float* w2  = (const float*)d_in[3];
    const float* w3  = (const float*)d_in[4];
    const float* w4  = (const float*)d_in[5];
    const float* w5  = (const float*)d_in[6];
    const float* w6  = (const float*)d_in[7];
    const float* w7  = (const float*)d_in[8];
    const float* w8  = (const float*)d_in[9];
    const float* w9  = (const float*)d_in[10];
    const float* w10 = (const float*)d_in[11];
    const float* w11 = (const float*)d_in[12];
    const float* gm  = (const float*)d_in[13];
    const float* bt  = (const float*)d_in[14];
    const float* mn  = (const float*)d_in[15];
    const float* vr  = (const float*)d_in[16];
    const float* wf  = (const float*)d_in[17];
    const float* bf  = (const float*)d_in[18];
    float* out = (float*)d_out;

    unsigned short* frag = (unsigned short*)d_ws;
    float* SCg = (float*)((char*)d_ws + 16384);
    float* SHg = (float*)((char*)d_ws + 16576);
    float* BFg = (float*)((char*)d_ws + 16768);
    float* Tws = (float*)((char*)d_ws + TWS_OFF);

    hipLaunchKernelGGL(prep_kernel, dim3(32), dim3(256), 0, stream,
                       w0, w1, w2, w3, w4, w5, w6, w7, w8, w9, w10, w11,
                       gm, bt, mn, vr, wf, bf, frag, SCg, SHg, BFg);

    dim3 block(256);
    hipLaunchKernelGGL(gemm_kernel, dim3(GRID), block, 0, stream,
                       x, frag, Tws);
    hipLaunchKernelGGL(tail_kernel, dim3(GRID), block, 0, stream,
                       Tws, w0, w1, w2, w3, w4, w5, w6, w7, w8, w9, w10, w11,
                       wf, SCg, SHg, BFg, out);
}

// Round 10
// 397.441 us; speedup vs baseline: 1.3072x; 1.1028x over previous
//
#include <hip/hip_runtime.h>

#define NROWS 500000
#define DD 128
#define NSTACK 12
#define BNEPS 1e-3f
#define NCOL 50
#define TRS 51            // trow stride in floats (204B: odd stride -> <=2-way LDS banking)

// packed tail-weight blob layout (floats)
#define WY   0            // [0,1056): y-part weights, layer i at 8*i*(i-1), 16*i floats
#define WFo  1056         // [1056,1152): wf[0..95] (y-part rows)
#define WSC  1152         // [1152,1200): SC = gamma*rsqrt(var+eps)
#define WSH  1200         // [1200,1248): SH = beta - mean*SC
#define WBF  1248         // [1248,1250): bf
#define WTOT 1250

typedef float  v2f    __attribute__((ext_vector_type(2)));
typedef float  v4f    __attribute__((ext_vector_type(4)));
typedef float  f32x4  __attribute__((ext_vector_type(4)));
typedef __bf16 bf16x8 __attribute__((ext_vector_type(8)));

__device__ __forceinline__ unsigned short f2bf_rn(float f) {
    unsigned u = __float_as_uint(f);
    return (unsigned short)((u + 0x7FFFu + ((u >> 16) & 1u)) >> 16);
}

// -------- workspace layout (bytes) --------
//  [0,     16384)  ushort frag[4][4][64][8]   B fragments, bf16, MFMA fragment order
//  [16800, 21800)  float  WT[1250]            packed tail weights (see above)

__global__ void prep_kernel(
    const float* __restrict__ w0,  const float* __restrict__ w1,
    const float* __restrict__ w2,  const float* __restrict__ w3,
    const float* __restrict__ w4,  const float* __restrict__ w5,
    const float* __restrict__ w6,  const float* __restrict__ w7,
    const float* __restrict__ w8,  const float* __restrict__ w9,
    const float* __restrict__ w10, const float* __restrict__ w11,
    const float* __restrict__ gamma_, const float* __restrict__ beta_,
    const float* __restrict__ mean_,  const float* __restrict__ var_,
    const float* __restrict__ wf,     const float* __restrict__ bfv,
    unsigned short* __restrict__ frag, float* __restrict__ wt)
{
    const float* ws[NSTACK] = {w0,w1,w2,w3,w4,w5,w6,w7,w8,w9,w10,w11};
    const int f = blockIdx.x * 256 + threadIdx.x;

    if (f < 8192) {
        // B fragments: f -> (kt,nt,lane,j); k = kt*32 + (lane>>4)*8 + j,
        // n = nt*16 + (lane&15). n<48: ws[n>>2][16*(n>>2)+4k+(n&3)];
        // n in {48,49}: wf[96+2k+(n-48)]; n>=50: 0 pad.
        const int j    = f & 7;
        const int lane = (f >> 3) & 63;
        const int nt   = (f >> 9) & 3;
        const int kt   = f >> 11;
        const int k    = kt * 32 + (lane >> 4) * 8 + j;
        const int n    = nt * 16 + (lane & 15);
        float val = 0.f;
        if (n < 48) {
            const int i = n >> 2, u = n & 3;
            val = ws[i][16 * i + 4 * k + u];
        } else if (n < NCOL) {
            val = wf[96 + 2 * k + (n - 48)];
        }
        frag[f] = f2bf_rn(val);
        return;
    }

    const int g = f - 8192;
    if (g >= WTOT) return;

    float val;
    if (g < WFo) {
        // y-part weights: find layer L with 8L(L-1) <= g < 8(L+1)L
        int L = 1;
#pragma unroll 1
        for (int t = 2; t <= 11; ++t)
            if (g >= 8 * t * (t - 1)) L = t;
        val = ws[L][g - 8 * L * (L - 1)];
    } else if (g < WSC) {
        val = wf[g - WFo];
    } else if (g < WSH) {
        const int u = g - WSC;
        val = gamma_[u] * __frsqrt_rn(var_[u] + BNEPS);
    } else if (g < WBF) {
        const int u = g - WSH;
        const float s = gamma_[u] * __frsqrt_rn(var_[u] + BNEPS);
        val = beta_[u] - mean_[u] * s;
    } else {
        val = bfv[g - WBF];
    }
    wt[g] = val;
}

// Main kernel: 4 waves x 64 rows = 256 rows/block, one tile per block.
// KEY CHANGE vs R5: tail weights come from LDS (broadcast ds_read_b128 with
// compile-time immediate offsets) instead of SMEM s_load. SMEM returns
// out-of-order -> every s_load use forces lgkmcnt(0) drains (also draining
// ds_reads); with ~100 SGPRs the tail needed ~20+ such batches per tile —
// the invariant ~90%-stall across R0-R8. DS returns in-order -> fine-grained
// lgkmcnt(N), no drains. Tail stays fully unrolled; y2 stays in registers
// (R7's loop-carried LDS roundtrip was the failure mode, not LDS weights).
__global__ __launch_bounds__(256, 2) void predict_kernel(
    const float* __restrict__ x,
    const unsigned short* __restrict__ frag,
    const float* __restrict__ WT,
    float* __restrict__ out)
{
    __shared__ __align__(16) float trow[256 * TRS];   // 52224 B
    __shared__ __align__(16) float wlds[WTOT];        // 5000 B -> 57224 B, 2 blk/CU

    const int tid  = threadIdx.x;
    const int lane = tid & 63;
    const int wv   = tid >> 6;
    const int rowbase = blockIdx.x * 256 + wv * 64;
    const int m = lane & 15;
    const int q = lane >> 4;

    // ---- stage packed tail weights (5KB, L2-hot), then ONE barrier ----
#pragma unroll 1
    for (int e = tid; e < WTOT; e += 256)
        wlds[e] = WT[e];
    __syncthreads();                                  // wlds visible to all waves

    // ---- Phase 1: MFMA GEMM ----
    const float* arow[4];
#pragma unroll
    for (int mt = 0; mt < 4; ++mt) {
        int r = rowbase + mt * 16 + m;
        if (r > NROWS - 1) r = NROWS - 1;             // tail clamp (stores predicated)
        arow[mt] = x + (size_t)r * DD + q * 8;
    }

    f32x4 acc[4][4];
#pragma unroll
    for (int mt = 0; mt < 4; ++mt)
#pragma unroll
        for (int nt = 0; nt < 4; ++nt) acc[mt][nt] = (f32x4){0.f, 0.f, 0.f, 0.f};

#pragma unroll
    for (int kt = 0; kt < 4; ++kt) {
        bf16x8 bfrag[4];
#pragma unroll
        for (int nt = 0; nt < 4; ++nt)
            bfrag[nt] = *(const bf16x8*)(frag + (((kt * 4 + nt) * 64 + lane) << 3));
#pragma unroll
        for (int mt = 0; mt < 4; ++mt) {
            const v4f a0 = *(const v4f*)(arow[mt] + kt * 32);
            const v4f a1 = *(const v4f*)(arow[mt] + kt * 32 + 4);
            bf16x8 av;
#pragma unroll
            for (int e = 0; e < 4; ++e) {
                av[e]     = (__bf16)a0[e];            // v_cvt_pk_bf16_f32
                av[4 + e] = (__bf16)a1[e];
            }
#pragma unroll
            for (int nt = 0; nt < 4; ++nt)
                acc[mt][nt] = __builtin_amdgcn_mfma_f32_16x16x32_bf16(
                    av, bfrag[nt], acc[mt][nt], 0, 0, 0);
        }
    }

    // ---- Phase 1.5: C-frag -> row-major LDS (wave-private region) ----
    // C/D layout: col = lane&15, row = (lane>>4)*4 + reg   [m89/m91]
    float* tr = &trow[wv * 64 * TRS];
#pragma unroll
    for (int mt = 0; mt < 4; ++mt)
#pragma unroll
        for (int nt = 0; nt < 4; ++nt) {
            const int c = nt * 16 + m;
            if (c < NCOL) {
#pragma unroll
                for (int r = 0; r < 4; ++r)
                    tr[(mt * 16 + q * 4 + r) * TRS + c] = acc[mt][nt][r];
            }
        }

    // ---- Phase 2: per-lane recurrence, unrolled, LDS-broadcast weights ----
    const float* myT = &trow[(wv * 64 + lane) * TRS];

    v2f y2[NSTACK * 2];                               // even-aligned pairs, in regs
#pragma unroll
    for (int i = 0; i < NSTACK; ++i) {
        v2f ac01[2], ac23[2];
        ac01[0] = *(const v2f*)(myT + 4 * i);         // ds_read_b64 (per-lane)
        ac23[0] = *(const v2f*)(myT + 4 * i + 2);
        ac01[1] = (v2f){0.f, 0.f};
        ac23[1] = (v2f){0.f, 0.f};
        const float* wyi = &wlds[WY + 8 * i * (i - 1)];
#pragma unroll
        for (int mr = 0; mr < 4 * i; ++mr) {
            const int yi = (i - 1 - (mr >> 2)) * 4 + (mr & 3);
            const float hvs = y2[yi >> 1][yi & 1];
            const v2f hv2 = {hvs, hvs};               // op_sel splat
            const v4f wr4 = *(const v4f*)(wyi + 4 * mr);   // ds_read_b128 broadcast
            ac01[mr & 1] += hv2 * (v2f){wr4.x, wr4.y};
            ac23[mr & 1] += hv2 * (v2f){wr4.z, wr4.w};
        }
        const v2f a01 = ac01[0] + ac01[1];
        const v2f a23 = ac23[0] + ac23[1];
        const v2f sc01 = *(const v2f*)(&wlds[WSC + 4 * i]);
        const v2f sc23 = *(const v2f*)(&wlds[WSC + 4 * i + 2]);
        const v2f sh01 = *(const v2f*)(&wlds[WSH + 4 * i]);
        const v2f sh23 = *(const v2f*)(&wlds[WSH + 4 * i + 2]);
        v2f r01 = a01 * sc01 + sh01;
        v2f r23 = a23 * sc23 + sh23;
        r01.x = fmaxf(r01.x, 0.f); r01.y = fmaxf(r01.y, 0.f);
        r23.x = fmaxf(r23.x, 0.f); r23.y = fmaxf(r23.y, 0.f);
        y2[2 * i]     = r01;
        y2[2 * i + 1] = r23;
    }

    // ---- Phase 3: final logits (unrolled, LDS weights) + softmax ----
    v2f lc[2];
    lc[0] = *(const v2f*)(myT + 48) + *(const v2f*)(&wlds[WBF]);
    lc[1] = (v2f){0.f, 0.f};
#pragma unroll
    for (int mr = 0; mr < 48; mr += 2) {              // 2 wf rows per b128
        const v4f wr4 = *(const v4f*)(&wlds[WFo + 2 * mr]);
        const int yi0 = (11 - (mr >> 2)) * 4 + (mr & 3);
        const int yi1 = (11 - ((mr + 1) >> 2)) * 4 + ((mr + 1) & 3);
        const float h0 = y2[yi0 >> 1][yi0 & 1];
        const float h1 = y2[yi1 >> 1][yi1 & 1];
        lc[0] += (v2f){h0, h0} * (v2f){wr4.x, wr4.y};
        lc[1] += (v2f){h1, h1} * (v2f){wr4.z, wr4.w};
    }
    const v2f l01 = lc[0] + lc[1];

    const float mx = fmaxf(l01.x, l01.y);
    const float e0 = __expf(l01.x - mx);
    const float e1 = __expf(l01.y - mx);
    const float inv = 1.0f / (e0 + e1);

    const int row = rowbase + lane;
    if (row < NROWS)
        *(v2f*)(out + (size_t)row * 2) = (v2f){e0 * inv, e1 * inv};
}

extern "C" void kernel_launch(void* const* d_in, const int* in_sizes, int n_in,
                              void* d_out, int out_size, void* d_ws, size_t ws_size,
                              hipStream_t stream) {
    const float* x   = (const float*)d_in[0];
    const float* w0  = (const float*)d_in[1];
    const float* w1  = (const float*)d_in[2];
    const float* w2  = (const float*)d_in[3];
    const float* w3  = (const float*)d_in[4];
    const float* w4  = (const float*)d_in[5];
    const float* w5  = (const float*)d_in[6];
    const float* w6  = (const float*)d_in[7];
    const float* w7  = (const float*)d_in[8];
    const float* w8  = (const float*)d_in[9];
    const float* w9  = (const float*)d_in[10];
    const float* w10 = (const float*)d_in[11];
    const float* w11 = (const float*)d_in[12];
    const float* gm  = (const float*)d_in[13];
    const float* bt  = (const float*)d_in[14];
    const float* mn  = (const float*)d_in[15];
    const float* vr  = (const float*)d_in[16];
    const float* wf  = (const float*)d_in[17];
    const float* bf  = (const float*)d_in[18];
    float* out = (float*)d_out;

    unsigned short* frag = (unsigned short*)d_ws;
    float* WT = (float*)((char*)d_ws + 16800);

    // prep: 32 blocks for 8192 frag entries + 5 blocks for the 1250-float blob
    hipLaunchKernelGGL(prep_kernel, dim3(37), dim3(256), 0, stream,
                       w0, w1, w2, w3, w4, w5, w6, w7, w8, w9, w10, w11,
                       gm, bt, mn, vr, wf, bf, frag, WT);

    dim3 block(256);
    dim3 grid((NROWS + 255) / 256);   // 256 rows per block
    hipLaunchKernelGGL(predict_kernel, grid, block, 0, stream,
                       x, frag, WT, out);
}